// Round 1
// baseline (208.963 us; speedup 1.0000x reference)
//
#include <hip/hip_runtime.h>

#define SLOPE 0.01f

__device__ __forceinline__ float lrelu(float v) { return v >= 0.f ? v : SLOPE * v; }

// ---------------------------------------------------------------------------
// Geometry:
//   x: (3,24,24), padded by 16 each side -> xp (3,56,56)
//   patch (i,j) = xp[:, i:i+33, j:j+33], i,j in 0..23
//   conv1 5x5 VALID on xp once -> Y1 (128,52,52); patch's conv1 out = Y1[i+u, j+v]
//   pool phase (i&1,j&1): P[ph](128,25,25); patch pooled = P[ph][(i>>1)+a, (j>>1)+b]
//   conv2 once per phase -> Z2[ph](128,21,21); patch conv2 out = Z2[ph][(i>>1)+p, ...]
//   pool2 phase (i&3,j&3): Q[qph](128,10,10); patch pooled2 = Q[qph][(i>>2)+e, ...]
//   conv3 = per-patch dot over 5x5 window of Q  (GEMM 128 x 576 x 3200)
//   conv4/conv5/dense fused per patch.
// ---------------------------------------------------------------------------

// K1: conv1 over padded image -> Y1[oc][r][s], r,s in 0..51
__global__ __launch_bounds__(256) void k_conv1(const float* __restrict__ x,
                                               const float* __restrict__ w,
                                               const float* __restrict__ b,
                                               float* __restrict__ Y1) {
    int t = blockIdx.x * 256 + threadIdx.x;
    if (t >= 128 * 52 * 52) return;
    int oc = t / 2704;
    int pos = t % 2704;
    int r = pos / 52, s = pos % 52;
    float acc = b[oc];
    const float* wp = w + oc * 75;
    for (int c = 0; c < 3; ++c) {
        for (int ky = 0; ky < 5; ++ky) {
            int iy = r + ky - 16;
            if (iy < 0 || iy >= 24) continue;
            for (int kx = 0; kx < 5; ++kx) {
                int ix = s + kx - 16;
                if (ix < 0 || ix >= 24) continue;
                acc += x[c * 576 + iy * 24 + ix] * wp[(c * 5 + ky) * 5 + kx];
            }
        }
    }
    Y1[t] = lrelu(acc);
}

// K2: 4-phase max pool -> P[ph][c][A][B], A,B in 0..24
__global__ __launch_bounds__(256) void k_pool1(const float* __restrict__ Y1,
                                               float* __restrict__ P) {
    int t = blockIdx.x * 256 + threadIdx.x;
    if (t >= 4 * 128 * 625) return;
    int ph = t / (128 * 625);
    int rem = t % (128 * 625);
    int c = rem / 625;
    int A = (rem % 625) / 25, B = rem % 25;
    int py = ph >> 1, px = ph & 1;
    int r0 = 2 * A + py, s0 = 2 * B + px;
    const float* yp = Y1 + c * 2704;
    float m0 = fmaxf(yp[r0 * 52 + s0], yp[r0 * 52 + s0 + 1]);
    float m1 = fmaxf(yp[(r0 + 1) * 52 + s0], yp[(r0 + 1) * 52 + s0 + 1]);
    P[t] = fmaxf(m0, m1);
}

// K3: conv2 per phase -> Z2[ph][oc][A][B], A,B in 0..20
// grid: ph(4) x A(21) x oc_tile(4 of 32) = 336 blocks, 256 threads
__global__ __launch_bounds__(256) void k_conv2(const float* __restrict__ P,
                                               const float* __restrict__ w,
                                               const float* __restrict__ b,
                                               float* __restrict__ Z2) {
    __shared__ float sm[16000]; // [ic=128][ky=5][25]
    int bid = blockIdx.x;
    int ph = bid / 84;          // 84 = 21*4
    int rem = bid % 84;
    int A = rem / 4;
    int oc0 = (rem % 4) * 32;
    const float* Pp = P + ph * 128 * 625;
    for (int idx = threadIdx.x; idx < 16000; idx += 256) {
        int ic = idx / 125;
        int r = (idx % 125) / 25;
        int bb = idx % 25;
        sm[idx] = Pp[ic * 625 + (A + r) * 25 + bb];
    }
    __syncthreads();
    int oc = oc0 + (threadIdx.x >> 3);
    int bg = threadIdx.x & 7;
    if (bg >= 7) return;      // 21 = 7 groups * 3 cols
    int B0 = bg * 3;
    float a0 = b[oc], a1 = a0, a2 = a0;
    const float* wp = w + oc * 3200;
    for (int ic = 0; ic < 128; ++ic) {
        const float* smi = sm + ic * 125 + B0;
        const float* wi = wp + ic * 25;
#pragma unroll
        for (int ky = 0; ky < 5; ++ky) {
            const float* row = smi + ky * 25;
            float r0 = row[0], r1 = row[1], r2 = row[2], r3 = row[3];
            float r4 = row[4], r5 = row[5], r6 = row[6];
            const float* wk = wi + ky * 5;
            float w0 = wk[0], w1 = wk[1], w2 = wk[2], w3 = wk[3], w4 = wk[4];
            a0 += r0 * w0 + r1 * w1 + r2 * w2 + r3 * w3 + r4 * w4;
            a1 += r1 * w0 + r2 * w1 + r3 * w2 + r4 * w3 + r5 * w4;
            a2 += r2 * w0 + r3 * w1 + r4 * w2 + r5 * w3 + r6 * w4;
        }
    }
    float* zp = Z2 + ((ph * 128 + oc) * 21 + A) * 21;
    zp[B0] = lrelu(a0);
    zp[B0 + 1] = lrelu(a1);
    zp[B0 + 2] = lrelu(a2);
}

// K4: 16-phase second pool -> Q[qph][c][C][D], C,D in 0..9
__global__ __launch_bounds__(256) void k_pool2(const float* __restrict__ Z2,
                                               float* __restrict__ Q) {
    int t = blockIdx.x * 256 + threadIdx.x;
    if (t >= 16 * 128 * 100) return;
    int qph = t / 12800;
    int rem = t % 12800;
    int c = rem / 100;
    int C = (rem % 100) / 10, D = rem % 10;
    int iq = qph >> 2, jq = qph & 3;
    int ph1 = (iq & 1) * 2 + (jq & 1);
    int py2 = iq >> 1, px2 = jq >> 1;
    const float* zp = Z2 + (ph1 * 128 + c) * 441;
    int r0 = 2 * C + py2, s0 = 2 * D + px2;
    float m0 = fmaxf(zp[r0 * 21 + s0], zp[r0 * 21 + s0 + 1]);
    float m1 = fmaxf(zp[(r0 + 1) * 21 + s0], zp[(r0 + 1) * 21 + s0 + 1]);
    Q[t] = fmaxf(m0, m1);
}

// K5: conv3 as GEMM: H3[oc][n] = lrelu(b + sum_k W_n[k] * c3w[oc][k])
// 4 patches per block, 144 blocks, 256 threads = 128 oc x 2 k-halves
__global__ __launch_bounds__(256) void k_conv3(const float* __restrict__ Q,
                                               const float* __restrict__ w,
                                               const float* __restrict__ b,
                                               float* __restrict__ H3) {
    __shared__ float W[4][3200];
    __shared__ float red[4][128];
    int n0 = blockIdx.x * 4;
    for (int p = 0; p < 4; ++p) {
        int n = n0 + p;
        int i = n / 24, j = n % 24;
        int qph = (i & 3) * 4 + (j & 3);
        int C0 = i >> 2, D0 = j >> 2;
        const float* qp = Q + qph * 12800;
        for (int idx = threadIdx.x; idx < 3200; idx += 256) {
            int ic = idx / 25;
            int e = (idx % 25) / 5, f = idx % 5;
            W[p][idx] = qp[ic * 100 + (C0 + e) * 10 + (D0 + f)];
        }
    }
    __syncthreads();
    int oc = threadIdx.x & 127;
    int h = threadIdx.x >> 7;
    const float* wp = w + oc * 3200 + h * 1600;
    float acc[4] = {0.f, 0.f, 0.f, 0.f};
    for (int k = 0; k < 1600; k += 4) {
        float4 wv = *(const float4*)(wp + k);
#pragma unroll
        for (int p = 0; p < 4; ++p) {
            float4 qv = *(const float4*)(&W[p][h * 1600 + k]);
            acc[p] += qv.x * wv.x + qv.y * wv.y + qv.z * wv.z + qv.w * wv.w;
        }
    }
    if (h == 1) {
#pragma unroll
        for (int p = 0; p < 4; ++p) red[p][oc] = acc[p];
    }
    __syncthreads();
    if (h == 0) {
        float bb = b[oc];
#pragma unroll
        for (int p = 0; p < 4; ++p) {
            float v = bb + acc[p] + red[p][oc];
            H3[oc * 576 + n0 + p] = lrelu(v);
        }
    }
}

// K6: fused conv4 + conv5 + dense per patch. block per patch, 256 threads.
__global__ __launch_bounds__(256) void k_tail(const float* __restrict__ H3,
                                              const float* __restrict__ c4w,
                                              const float* __restrict__ c4b,
                                              const float* __restrict__ c5w,
                                              const float* __restrict__ c5b,
                                              const float* __restrict__ dw,
                                              const float* __restrict__ db,
                                              float* __restrict__ out) {
    __shared__ float h3[128];
    __shared__ float h4[256];
    __shared__ float h5[128];
    int n = blockIdx.x;
    int tid = threadIdx.x;
    if (tid < 128) h3[tid] = H3[tid * 576 + n];
    __syncthreads();
    { // conv4: 256 outputs
        float acc = c4b[tid];
        const float* wp = c4w + tid * 128;
        for (int k = 0; k < 128; k += 4) {
            float4 wv = *(const float4*)(wp + k);
            acc += h3[k] * wv.x + h3[k + 1] * wv.y + h3[k + 2] * wv.z + h3[k + 3] * wv.w;
        }
        h4[tid] = lrelu(acc);
    }
    __syncthreads();
    if (tid < 128) { // conv5: 128 outputs
        float acc = c5b[tid];
        const float* wp = c5w + tid * 256;
        for (int k = 0; k < 256; k += 4) {
            float4 wv = *(const float4*)(wp + k);
            acc += h4[k] * wv.x + h4[k + 1] * wv.y + h4[k + 2] * wv.z + h4[k + 3] * wv.w;
        }
        h5[tid] = lrelu(acc);
    }
    __syncthreads();
    for (int o = tid; o < 512; o += 256) { // dense: 512 outputs
        float acc = db[o];
        const float* wp = dw + o * 128;
        for (int k = 0; k < 128; k += 4) {
            float4 wv = *(const float4*)(wp + k);
            acc += h5[k] * wv.x + h5[k + 1] * wv.y + h5[k + 2] * wv.z + h5[k + 3] * wv.w;
        }
        out[o * 576 + n] = acc;
    }
}

extern "C" void kernel_launch(void* const* d_in, const int* in_sizes, int n_in,
                              void* d_out, int out_size, void* d_ws, size_t ws_size,
                              hipStream_t stream) {
    const float* x   = (const float*)d_in[0];
    const float* c1w = (const float*)d_in[1];
    const float* c1b = (const float*)d_in[2];
    const float* c2w = (const float*)d_in[3];
    const float* c2b = (const float*)d_in[4];
    const float* c3w = (const float*)d_in[5];
    const float* c3b = (const float*)d_in[6];
    const float* c4w = (const float*)d_in[7];
    const float* c4b = (const float*)d_in[8];
    const float* c5w = (const float*)d_in[9];
    const float* c5b = (const float*)d_in[10];
    const float* dw  = (const float*)d_in[11];
    const float* db  = (const float*)d_in[12];
    float* out = (float*)d_out;

    float* ws = (float*)d_ws;
    float* Y1 = ws;                    // 128*52*52   = 346112
    float* P  = Y1 + 346112;           // 4*128*25*25 = 320000
    float* Z2 = P + 320000;            // 4*128*21*21 = 225792
    float* Q  = Z2 + 225792;           // 16*128*10*10= 204800
    float* H3 = Q + 204800;            // 128*576     = 73728

    k_conv1<<<(128 * 52 * 52 + 255) / 256, 256, 0, stream>>>(x, c1w, c1b, Y1);
    k_pool1<<<(4 * 128 * 625) / 256, 256, 0, stream>>>(Y1, P);
    k_conv2<<<4 * 21 * 4, 256, 0, stream>>>(P, c2w, c2b, Z2);
    k_pool2<<<(16 * 128 * 100) / 256, 256, 0, stream>>>(Z2, Q);
    k_conv3<<<576 / 4, 256, 0, stream>>>(Q, c3w, c3b, H3);
    k_tail<<<576, 256, 0, stream>>>(H3, c4w, c4b, c5w, c5b, dw, db, out);
}

// Round 2
// 125.465 us; speedup vs baseline: 1.6655x; 1.6655x over previous
//
#include <hip/hip_runtime.h>

#define SLOPE 0.01f

typedef __attribute__((ext_vector_type(8))) short short8;
typedef __attribute__((ext_vector_type(4))) float f32x4;

__device__ __forceinline__ float lrelu(float v) { return v >= 0.f ? v : SLOPE * v; }

__device__ __forceinline__ unsigned short f2bf(float f) {
    union { float f; unsigned int u; } v; v.f = f;
    unsigned int r = v.u + 0x7fffu + ((v.u >> 16) & 1u);
    return (unsigned short)(r >> 16);
}
__device__ __forceinline__ float bf2f(unsigned short h) {
    union { unsigned int u; float f; } v; v.u = ((unsigned int)h) << 16;
    return v.f;
}

// ---------------------------------------------------------------------------
// Layouts (all channel-contiguous):
//   Y1t  f32  [r=52][s=52][oc=128]
//   P2   bf16 [ph=4][A=25][B=25][ic=128]
//   Z2   bf16 [ph=4][A=21][B=21][oc=128]
//   Q2   bf16 [qph=16][C=10][D=10][ic=128]
//   H3   f32  [n=576][oc=128]
//   W1f  f32  [k=75][oc=128]          (k = c*25 + ky*5 + kx)
//   W2   bf16 [oc=128][kpos=25][ic=128]
//   W3   bf16 [oc=128][kpos=25][ic=128]
// MFMA k-order for conv2/conv3: k = kpos*128 + ic  (8 consecutive k = 8 ic)
// ---------------------------------------------------------------------------

// reorder c1w (128,3,5,5) -> W1f[k][oc] f32
__global__ __launch_bounds__(256) void k_w1(const float* __restrict__ in,
                                            float* __restrict__ out) {
    int t = blockIdx.x * 256 + threadIdx.x;
    if (t >= 9600) return;
    int oc = t & 127;
    int rest = t >> 7;           // c*25 + kpos
    int kpos = rest % 25, c = rest / 25;
    out[t] = in[(oc * 3 + c) * 25 + kpos];
}

// reorder (128,128,5,5) f32 -> [oc][kpos][ic] bf16
__global__ __launch_bounds__(256) void k_wre(const float* __restrict__ in,
                                             unsigned short* __restrict__ out) {
    int t = blockIdx.x * 256 + threadIdx.x;   // t = (oc*25+kpos)*128 + ic
    int ic = t & 127;
    int kpos = (t >> 7) % 25;
    int oc = (t >> 7) / 25;
    out[t] = f2bf(in[(oc * 128 + ic) * 25 + kpos]);
}

// conv1 over padded image -> Y1t[r][s][oc]
__global__ __launch_bounds__(256) void k_conv1(const float* __restrict__ x,
                                               const float* __restrict__ W1f,
                                               const float* __restrict__ b,
                                               float* __restrict__ Y1t) {
    int t = blockIdx.x * 256 + threadIdx.x;   // 346112 = 2704*128
    int oc = t & 127;
    int pos = t >> 7;
    int r = pos / 52, s = pos % 52;
    float acc = b[oc];
    for (int c = 0; c < 3; ++c) {
        for (int ky = 0; ky < 5; ++ky) {
            int iy = r + ky - 16;
            if (iy < 0 || iy >= 24) continue;
            for (int kx = 0; kx < 5; ++kx) {
                int ix = s + kx - 16;
                if (ix < 0 || ix >= 24) continue;
                acc += x[c * 576 + iy * 24 + ix] * W1f[(c * 25 + ky * 5 + kx) * 128 + oc];
            }
        }
    }
    Y1t[t] = lrelu(acc);
}

// 4-phase pool -> P2 bf16 [ph][A][B][ic]
__global__ __launch_bounds__(256) void k_pool1(const float* __restrict__ Y1t,
                                               unsigned short* __restrict__ P2) {
    int t = blockIdx.x * 256 + threadIdx.x;   // 320000 = 4*25*25*128
    int ic = t & 127;
    int rest = t >> 7;
    int B = rest % 25;
    int A = (rest / 25) % 25;
    int ph = rest / 625;
    int py = ph >> 1, px = ph & 1;
    int r0 = 2 * A + py, s0 = 2 * B + px;
    const float* y00 = Y1t + (r0 * 52 + s0) * 128 + ic;
    float m0 = fmaxf(y00[0], y00[128]);
    float m1 = fmaxf(y00[52 * 128], y00[53 * 128]);
    P2[t] = f2bf(fmaxf(m0, m1));
}

// conv2 via MFMA: per block = (ph, A-row, oc-half). 4 waves x 16 oc each.
// Each wave: 2 position-tiles (B0=0 and B0=5), K = 25 kpos x 128 ic.
__global__ __launch_bounds__(256) void k_conv2(const unsigned short* __restrict__ P2,
                                               const unsigned short* __restrict__ W2,
                                               const float* __restrict__ bias,
                                               unsigned short* __restrict__ Z2) {
    int bid = blockIdx.x;          // 168 = 4ph * 21A * 2oh
    int ph = bid / 42;
    int rem = bid % 42;
    int A = rem >> 1;
    int oh = rem & 1;
    int tid = threadIdx.x, lane = tid & 63, wid = tid >> 6;
    int m = lane & 15, bq = lane >> 4;
    int oc0 = oh * 64 + wid * 16;
    const unsigned short* wbase = W2 + (oc0 + m) * 3200 + 8 * bq;
    const unsigned short* pbase = P2 + ((ph * 25 + A) * 25) * 128 + 8 * bq;
    f32x4 acc0 = {0.f, 0.f, 0.f, 0.f}, acc1 = {0.f, 0.f, 0.f, 0.f};
    for (int kpos = 0; kpos < 25; ++kpos) {
        int ky = kpos / 5, kx = kpos % 5;
        const unsigned short* wp = wbase + kpos * 128;
        const unsigned short* p0 = pbase + (ky * 25 + m + kx) * 128;
        const unsigned short* p1 = p0 + 5 * 128;
#pragma unroll
        for (int ic0 = 0; ic0 < 128; ic0 += 32) {
            short8 a  = *(const short8*)(wp + ic0);
            short8 b0 = *(const short8*)(p0 + ic0);
            short8 b1 = *(const short8*)(p1 + ic0);
            acc0 = __builtin_amdgcn_mfma_f32_16x16x32_bf16(a, b0, acc0, 0, 0, 0);
            acc1 = __builtin_amdgcn_mfma_f32_16x16x32_bf16(a, b1, acc1, 0, 0, 0);
        }
    }
    int ocb = oc0 + 4 * bq;
    float b0v = bias[ocb], b1v = bias[ocb + 1], b2v = bias[ocb + 2], b3v = bias[ocb + 3];
    unsigned short* zrow = Z2 + ((ph * 21 + A) * 21) * 128 + ocb;
    {
        ushort4 pk;
        pk.x = f2bf(lrelu(acc0.x + b0v));
        pk.y = f2bf(lrelu(acc0.y + b1v));
        pk.z = f2bf(lrelu(acc0.z + b2v));
        pk.w = f2bf(lrelu(acc0.w + b3v));
        *(ushort4*)(zrow + m * 128) = pk;       // B = m (0..15)
    }
    if (m >= 11) {                              // B = m+5 (16..20), avoid overlap
        ushort4 pk;
        pk.x = f2bf(lrelu(acc1.x + b0v));
        pk.y = f2bf(lrelu(acc1.y + b1v));
        pk.z = f2bf(lrelu(acc1.z + b2v));
        pk.w = f2bf(lrelu(acc1.w + b3v));
        *(ushort4*)(zrow + (m + 5) * 128) = pk;
    }
}

// 16-phase pool -> Q2 bf16 [qph][C][D][ic]
__global__ __launch_bounds__(256) void k_pool2(const unsigned short* __restrict__ Z2,
                                               unsigned short* __restrict__ Q2) {
    int t = blockIdx.x * 256 + threadIdx.x;   // 204800 = 16*10*10*128
    int ic = t & 127;
    int rest = t >> 7;
    int D = rest % 10;
    int C = (rest / 10) % 10;
    int qph = rest / 100;
    int iq = qph >> 2, jq = qph & 3;
    int ph1 = (iq & 1) * 2 + (jq & 1);
    int py2 = iq >> 1, px2 = jq >> 1;
    int r0 = 2 * C + py2, s0 = 2 * D + px2;
    const unsigned short* z00 = Z2 + ((ph1 * 21 + r0) * 21 + s0) * 128 + ic;
    float m0 = fmaxf(bf2f(z00[0]), bf2f(z00[128]));
    float m1 = fmaxf(bf2f(z00[21 * 128]), bf2f(z00[22 * 128]));
    Q2[t] = f2bf(fmaxf(m0, m1));
}

// conv3 via MFMA: block = 16 patches, 4 waves x 32 oc (2 oc-tiles each).
__global__ __launch_bounds__(256) void k_conv3(const unsigned short* __restrict__ Q2,
                                               const unsigned short* __restrict__ W3,
                                               const float* __restrict__ bias,
                                               float* __restrict__ H3) {
    int n0 = blockIdx.x * 16;     // 36 blocks
    int tid = threadIdx.x, lane = tid & 63, wid = tid >> 6;
    int m = lane & 15, bq = lane >> 4;
    int p = n0 + m;
    int i = p / 24, j = p % 24;
    int qph = (i & 3) * 4 + (j & 3);
    const unsigned short* qbase = Q2 + ((qph * 10 + (i >> 2)) * 10 + (j >> 2)) * 128 + 8 * bq;
    int oc0 = wid * 32;
    const unsigned short* wbase = W3 + (oc0 + m) * 3200 + 8 * bq;
    f32x4 acc0 = {0.f, 0.f, 0.f, 0.f}, acc1 = {0.f, 0.f, 0.f, 0.f};
    for (int kpos = 0; kpos < 25; ++kpos) {
        int e = kpos / 5, f = kpos % 5;
        const unsigned short* qp = qbase + (e * 10 + f) * 128;
        const unsigned short* wp = wbase + kpos * 128;
#pragma unroll
        for (int ic0 = 0; ic0 < 128; ic0 += 32) {
            short8 bf = *(const short8*)(qp + ic0);
            short8 a0 = *(const short8*)(wp + ic0);
            short8 a1 = *(const short8*)(wp + 16 * 3200 + ic0);
            acc0 = __builtin_amdgcn_mfma_f32_16x16x32_bf16(a0, bf, acc0, 0, 0, 0);
            acc1 = __builtin_amdgcn_mfma_f32_16x16x32_bf16(a1, bf, acc1, 0, 0, 0);
        }
    }
    float* h = H3 + p * 128;
    int ocb0 = oc0 + 4 * bq;
    f32x4 o0;
    o0.x = lrelu(acc0.x + bias[ocb0]);
    o0.y = lrelu(acc0.y + bias[ocb0 + 1]);
    o0.z = lrelu(acc0.z + bias[ocb0 + 2]);
    o0.w = lrelu(acc0.w + bias[ocb0 + 3]);
    *(f32x4*)(h + ocb0) = o0;
    int ocb1 = ocb0 + 16;
    f32x4 o1;
    o1.x = lrelu(acc1.x + bias[ocb1]);
    o1.y = lrelu(acc1.y + bias[ocb1 + 1]);
    o1.z = lrelu(acc1.z + bias[ocb1 + 2]);
    o1.w = lrelu(acc1.w + bias[ocb1 + 3]);
    *(f32x4*)(h + ocb1) = o1;
}

// fused conv4+conv5+dense, 4 patches per block (weight reuse x4)
__global__ __launch_bounds__(256) void k_tail(const float* __restrict__ H3,
                                              const float* __restrict__ c4w,
                                              const float* __restrict__ c4b,
                                              const float* __restrict__ c5w,
                                              const float* __restrict__ c5b,
                                              const float* __restrict__ dw,
                                              const float* __restrict__ db,
                                              float* __restrict__ out) {
    __shared__ float h3[4][128];
    __shared__ float h4[4][256];
    __shared__ float h5[4][128];
    int n0 = blockIdx.x * 4;      // 144 blocks
    int tid = threadIdx.x;
    if (tid < 128) {
#pragma unroll
        for (int p = 0; p < 4; ++p) h3[p][tid] = H3[(n0 + p) * 128 + tid];
    }
    __syncthreads();
    {
        float a0 = c4b[tid], a1 = a0, a2 = a0, a3 = a0;
        const float* wp = c4w + tid * 128;
        for (int k = 0; k < 128; k += 4) {
            float4 wv = *(const float4*)(wp + k);
            a0 += h3[0][k] * wv.x + h3[0][k + 1] * wv.y + h3[0][k + 2] * wv.z + h3[0][k + 3] * wv.w;
            a1 += h3[1][k] * wv.x + h3[1][k + 1] * wv.y + h3[1][k + 2] * wv.z + h3[1][k + 3] * wv.w;
            a2 += h3[2][k] * wv.x + h3[2][k + 1] * wv.y + h3[2][k + 2] * wv.z + h3[2][k + 3] * wv.w;
            a3 += h3[3][k] * wv.x + h3[3][k + 1] * wv.y + h3[3][k + 2] * wv.z + h3[3][k + 3] * wv.w;
        }
        h4[0][tid] = lrelu(a0); h4[1][tid] = lrelu(a1);
        h4[2][tid] = lrelu(a2); h4[3][tid] = lrelu(a3);
    }
    __syncthreads();
    if (tid < 128) {
        float a0 = c5b[tid], a1 = a0, a2 = a0, a3 = a0;
        const float* wp = c5w + tid * 256;
        for (int k = 0; k < 256; k += 4) {
            float4 wv = *(const float4*)(wp + k);
            a0 += h4[0][k] * wv.x + h4[0][k + 1] * wv.y + h4[0][k + 2] * wv.z + h4[0][k + 3] * wv.w;
            a1 += h4[1][k] * wv.x + h4[1][k + 1] * wv.y + h4[1][k + 2] * wv.z + h4[1][k + 3] * wv.w;
            a2 += h4[2][k] * wv.x + h4[2][k + 1] * wv.y + h4[2][k + 2] * wv.z + h4[2][k + 3] * wv.w;
            a3 += h4[3][k] * wv.x + h4[3][k + 1] * wv.y + h4[3][k + 2] * wv.z + h4[3][k + 3] * wv.w;
        }
        h5[0][tid] = lrelu(a0); h5[1][tid] = lrelu(a1);
        h5[2][tid] = lrelu(a2); h5[3][tid] = lrelu(a3);
    }
    __syncthreads();
    for (int o = tid; o < 512; o += 256) {
        float a0 = db[o], a1 = a0, a2 = a0, a3 = a0;
        const float* wp = dw + o * 128;
        for (int k = 0; k < 128; k += 4) {
            float4 wv = *(const float4*)(wp + k);
            a0 += h5[0][k] * wv.x + h5[0][k + 1] * wv.y + h5[0][k + 2] * wv.z + h5[0][k + 3] * wv.w;
            a1 += h5[1][k] * wv.x + h5[1][k + 1] * wv.y + h5[1][k + 2] * wv.z + h5[1][k + 3] * wv.w;
            a2 += h5[2][k] * wv.x + h5[2][k + 1] * wv.y + h5[2][k + 2] * wv.z + h5[2][k + 3] * wv.w;
            a3 += h5[3][k] * wv.x + h5[3][k + 1] * wv.y + h5[3][k + 2] * wv.z + h5[3][k + 3] * wv.w;
        }
        out[o * 576 + n0 + 0] = a0;
        out[o * 576 + n0 + 1] = a1;
        out[o * 576 + n0 + 2] = a2;
        out[o * 576 + n0 + 3] = a3;
    }
}

extern "C" void kernel_launch(void* const* d_in, const int* in_sizes, int n_in,
                              void* d_out, int out_size, void* d_ws, size_t ws_size,
                              hipStream_t stream) {
    const float* x   = (const float*)d_in[0];
    const float* c1w = (const float*)d_in[1];
    const float* c1b = (const float*)d_in[2];
    const float* c2w = (const float*)d_in[3];
    const float* c2b = (const float*)d_in[4];
    const float* c3w = (const float*)d_in[5];
    const float* c3b = (const float*)d_in[6];
    const float* c4w = (const float*)d_in[7];
    const float* c4b = (const float*)d_in[8];
    const float* c5w = (const float*)d_in[9];
    const float* c5b = (const float*)d_in[10];
    const float* dw  = (const float*)d_in[11];
    const float* db  = (const float*)d_in[12];
    float* out = (float*)d_out;

    float* ws = (float*)d_ws;
    float*          Y1t = ws;                                  // 346112 f32
    unsigned short* P2  = (unsigned short*)(ws + 346112);      // 320000 bf16 (160000 slots)
    unsigned short* Z2  = (unsigned short*)(ws + 506112);      // 225792 bf16 (112896 slots)
    unsigned short* Q2  = (unsigned short*)(ws + 619008);      // 204800 bf16 (102400 slots)
    float*          H3  = ws + 721408;                         // 73728 f32
    float*          W1f = ws + 795136;                         // 9600 f32
    unsigned short* W2  = (unsigned short*)(ws + 804736);      // 409600 bf16 (204800 slots)
    unsigned short* W3  = (unsigned short*)(ws + 1009536);     // 409600 bf16 (204800 slots)
    // total: 1214336 f32 slots = 4.86 MB

    k_w1   <<<38, 256, 0, stream>>>(c1w, W1f);
    k_wre  <<<1600, 256, 0, stream>>>(c2w, W2);
    k_wre  <<<1600, 256, 0, stream>>>(c3w, W3);
    k_conv1<<<1352, 256, 0, stream>>>(x, W1f, c1b, Y1t);
    k_pool1<<<1250, 256, 0, stream>>>(Y1t, P2);
    k_conv2<<<168, 256, 0, stream>>>(P2, W2, c2b, Z2);
    k_pool2<<<800, 256, 0, stream>>>(Z2, Q2);
    k_conv3<<<36, 256, 0, stream>>>(Q2, W3, c3b, H3);
    k_tail <<<144, 256, 0, stream>>>(H3, c4w, c4b, c5w, c5b, dw, db, out);
}

// Round 4
// 104.746 us; speedup vs baseline: 1.9949x; 1.1978x over previous
//
#include <hip/hip_runtime.h>

#define SLOPE 0.01f

typedef __attribute__((ext_vector_type(8))) short short8;
typedef __attribute__((ext_vector_type(4))) float f32x4;

__device__ __forceinline__ float lrelu(float v) { return v >= 0.f ? v : SLOPE * v; }

__device__ __forceinline__ unsigned short f2bf(float f) {
    union { float f; unsigned int u; } v; v.f = f;
    unsigned int r = v.u + 0x7fffu + ((v.u >> 16) & 1u);
    return (unsigned short)(r >> 16);
}
__device__ __forceinline__ float bf2f(unsigned short h) {
    union { unsigned int u; float f; } v; v.u = ((unsigned int)h) << 16;
    return v.f;
}

// ---------------------------------------------------------------------------
// Workspace layout (f32 slot offsets):
//   P2   bf16 [ph=4][A=25][B=25][ic=128]   @ 0       (160000 f32 slots)
//   Z2   bf16 [ph=4][A=21][B=21][oc=128]   @ 160000  (112896)
//   W2   bf16 [oc=128][kpos=25][ic=128]    @ 272896  (204800)
//   W3   bf16 [oc=128][kpos=25][ic=128]    @ 477696  (204800)
// MFMA k-order for conv2/conv3: k = kpos*128 + ic
// ---------------------------------------------------------------------------

// K1: blocks [0,1250): fused conv1+pool1 -> P2.  blocks [1250,1506): W2/W3 transpose.
__global__ __launch_bounds__(256) void k_front(const float* __restrict__ x,
                                               const float* __restrict__ c1w,
                                               const float* __restrict__ c1b,
                                               const float* __restrict__ c2w,
                                               const float* __restrict__ c3w,
                                               unsigned short* __restrict__ P2,
                                               unsigned short* __restrict__ W2,
                                               unsigned short* __restrict__ W3) {
    __shared__ float smem[9600];
    int bid = blockIdx.x, tid = threadIdx.x;

    if (bid < 1250) {
        // stage all conv1 weights in LDS (layout unchanged: [oc][c][ky][kx])
        for (int idx = tid; idx < 9600; idx += 256) smem[idx] = c1w[idx];
        __syncthreads();

        int t = bid * 256 + tid;          // t in [0, 320000)
        int ic = t & 127;                 // = oc of conv1
        int rest = t >> 7;
        int B = rest % 25;
        int A = (rest / 25) % 25;
        int ph = rest / 625;
        int py = ph >> 1, px = ph & 1;
        int r0 = 2 * A + py, s0 = 2 * B + px;   // top-left of 2x2 pool window in Y1 coords

        float a00 = 0.f, a01 = 0.f, a10 = 0.f, a11 = 0.f;
        const float* lw = smem + ic * 75;
        for (int c = 0; c < 3; ++c) {
            const float* xc = x + c * 576;
            const float* lwc = lw + c * 25;
#pragma unroll
            for (int ky = 0; ky < 5; ++ky) {
                int iy = r0 + ky - 16;
                bool v0 = (iy >= 0) && (iy < 24);
                bool v1 = (iy + 1 >= 0) && (iy + 1 < 24);
                if (!v0 && !v1) continue;
#pragma unroll
                for (int kx = 0; kx < 5; ++kx) {
                    int ix = s0 + kx - 16;
                    float w = lwc[ky * 5 + kx];
                    bool u0 = (ix >= 0) && (ix < 24);
                    bool u1 = (ix + 1 >= 0) && (ix + 1 < 24);
                    float x00 = (v0 && u0) ? xc[iy * 24 + ix] : 0.f;
                    float x01 = (v0 && u1) ? xc[iy * 24 + ix + 1] : 0.f;
                    float x10 = (v1 && u0) ? xc[(iy + 1) * 24 + ix] : 0.f;
                    float x11 = (v1 && u1) ? xc[(iy + 1) * 24 + ix + 1] : 0.f;
                    a00 += x00 * w; a01 += x01 * w; a10 += x10 * w; a11 += x11 * w;
                }
            }
        }
        // lrelu is monotone -> pool(lrelu(h+b)) = lrelu(b + max(h))
        float mx = fmaxf(fmaxf(a00, a01), fmaxf(a10, a11));
        P2[t] = f2bf(lrelu(c1b[ic] + mx));
    } else {
        // W2/W3: one block per oc row, transpose [ic][kpos] -> [kpos][ic], f32 -> bf16
        int wbid = bid - 1250;            // 0..255
        const float* src = (wbid < 128) ? (c2w + wbid * 3200) : (c3w + (wbid - 128) * 3200);
        unsigned short* dst = (wbid < 128) ? (W2 + wbid * 3200) : (W3 + (wbid - 128) * 3200);
        for (int idx = tid; idx < 3200; idx += 256) smem[idx] = src[idx];
        __syncthreads();
        for (int idx = tid; idx < 3200; idx += 256) {
            int ic = idx & 127, kpos = idx >> 7;
            dst[idx] = f2bf(smem[ic * 25 + kpos]);
        }
    }
}

// K2: conv2 via MFMA (validated in R2) -> Z2[ph][A][B][oc]
__global__ __launch_bounds__(256) void k_conv2(const unsigned short* __restrict__ P2,
                                               const unsigned short* __restrict__ W2,
                                               const float* __restrict__ bias,
                                               unsigned short* __restrict__ Z2) {
    int bid = blockIdx.x;          // 168 = 4ph * 21A * 2oh
    int ph = bid / 42;
    int rem = bid % 42;
    int A = rem >> 1;
    int oh = rem & 1;
    int tid = threadIdx.x, lane = tid & 63, wid = tid >> 6;
    int m = lane & 15, bq = lane >> 4;
    int oc0 = oh * 64 + wid * 16;
    const unsigned short* wbase = W2 + (oc0 + m) * 3200 + 8 * bq;
    const unsigned short* pbase = P2 + ((ph * 25 + A) * 25) * 128 + 8 * bq;
    f32x4 acc0 = {0.f, 0.f, 0.f, 0.f}, acc1 = {0.f, 0.f, 0.f, 0.f};
    for (int kpos = 0; kpos < 25; ++kpos) {
        int ky = kpos / 5, kx = kpos % 5;
        const unsigned short* wp = wbase + kpos * 128;
        const unsigned short* p0 = pbase + (ky * 25 + m + kx) * 128;
        const unsigned short* p1 = p0 + 5 * 128;
#pragma unroll
        for (int ic0 = 0; ic0 < 128; ic0 += 32) {
            short8 a  = *(const short8*)(wp + ic0);
            short8 b0 = *(const short8*)(p0 + ic0);
            short8 b1 = *(const short8*)(p1 + ic0);
            acc0 = __builtin_amdgcn_mfma_f32_16x16x32_bf16(a, b0, acc0, 0, 0, 0);
            acc1 = __builtin_amdgcn_mfma_f32_16x16x32_bf16(a, b1, acc1, 0, 0, 0);
        }
    }
    int ocb = oc0 + 4 * bq;
    float b0v = bias[ocb], b1v = bias[ocb + 1], b2v = bias[ocb + 2], b3v = bias[ocb + 3];
    unsigned short* zrow = Z2 + ((ph * 21 + A) * 21) * 128 + ocb;
    {
        ushort4 pk;
        pk.x = f2bf(lrelu(acc0.x + b0v));
        pk.y = f2bf(lrelu(acc0.y + b1v));
        pk.z = f2bf(lrelu(acc0.z + b2v));
        pk.w = f2bf(lrelu(acc0.w + b3v));
        *(ushort4*)(zrow + m * 128) = pk;          // B = m (0..15)
    }
    if (m >= 11) {                                 // B = m+5 (16..20)
        ushort4 pk;
        pk.x = f2bf(lrelu(acc1.x + b0v));
        pk.y = f2bf(lrelu(acc1.y + b1v));
        pk.z = f2bf(lrelu(acc1.z + b2v));
        pk.w = f2bf(lrelu(acc1.w + b3v));
        *(ushort4*)(zrow + (m + 5) * 128) = pk;
    }
}

// K3: fused pool2 + conv3(MFMA) + conv4 + conv5 + dense. 144 blocks x 4 patches.
#define PSTRIDE 3208   // padded per-patch LDS stride (bf16 elems) to spread banks
__global__ __launch_bounds__(256) void k_fuse3(const unsigned short* __restrict__ Z2,
                                               const unsigned short* __restrict__ W3,
                                               const float* __restrict__ c3b,
                                               const float* __restrict__ c4w,
                                               const float* __restrict__ c4b,
                                               const float* __restrict__ c5w,
                                               const float* __restrict__ c5b,
                                               const float* __restrict__ dw,
                                               const float* __restrict__ db,
                                               float* __restrict__ out) {
    __shared__ unsigned short Qw[4 * PSTRIDE];   // 4 patch windows, [kpos=25][ic=128] each
    __shared__ float hbuf[2048];                 // h3[4][128] | h4[4][256] | h5[4][128]
    float* h3 = hbuf;
    float* h4 = hbuf + 512;
    float* h5 = hbuf + 1536;

    int bid = blockIdx.x, tid = threadIdx.x;
    int n0 = bid * 4;

    // ---- phase A: build pool2 windows into LDS ----
    for (int q = tid; q < 12800; q += 256) {
        int p = q / 3200;
        int rem = q - p * 3200;
        int kpos = rem >> 7, ic = rem & 127;
        int e = kpos / 5, f = kpos % 5;
        int n = n0 + p, i = n / 24, j = n % 24;
        int ph1 = (i & 1) * 2 + (j & 1);
        int C = (i >> 2) + e, D = (j >> 2) + f;
        int r0 = 2 * C + ((i >> 1) & 1), s0 = 2 * D + ((j >> 1) & 1);
        const unsigned short* z = Z2 + ((ph1 * 21 + r0) * 21 + s0) * 128 + ic;
        float m0 = fmaxf(bf2f(z[0]), bf2f(z[128]));
        float m1 = fmaxf(bf2f(z[21 * 128]), bf2f(z[22 * 128]));
        Qw[p * PSTRIDE + rem] = f2bf(fmaxf(m0, m1));
    }
    __syncthreads();

    // ---- phase B: conv3 MFMA (patch replicated over M columns) ----
    int lane = tid & 63, wid = tid >> 6;
    int m = lane & 15, bq = lane >> 4;
    int pm = m & 3;
    const unsigned short* wbase = W3 + (wid * 32 + m) * 3200 + 8 * bq;
    const unsigned short* qb = Qw + pm * PSTRIDE + 8 * bq;
    f32x4 acc0 = {0.f, 0.f, 0.f, 0.f}, acc1 = {0.f, 0.f, 0.f, 0.f};
    for (int kpos = 0; kpos < 25; ++kpos) {
        const unsigned short* qp = qb + kpos * 128;
        const unsigned short* wp = wbase + kpos * 128;
#pragma unroll
        for (int ic0 = 0; ic0 < 128; ic0 += 32) {
            short8 bf = *(const short8*)(qp + ic0);
            short8 a0 = *(const short8*)(wp + ic0);
            short8 a1 = *(const short8*)(wp + 16 * 3200 + ic0);
            acc0 = __builtin_amdgcn_mfma_f32_16x16x32_bf16(a0, bf, acc0, 0, 0, 0);
            acc1 = __builtin_amdgcn_mfma_f32_16x16x32_bf16(a1, bf, acc1, 0, 0, 0);
        }
    }
    if (m < 4) {   // D cols 0..3 hold the 4 real patches
        int ocb0 = wid * 32 + 4 * bq;
        h3[m * 128 + ocb0 + 0] = lrelu(acc0.x + c3b[ocb0 + 0]);
        h3[m * 128 + ocb0 + 1] = lrelu(acc0.y + c3b[ocb0 + 1]);
        h3[m * 128 + ocb0 + 2] = lrelu(acc0.z + c3b[ocb0 + 2]);
        h3[m * 128 + ocb0 + 3] = lrelu(acc0.w + c3b[ocb0 + 3]);
        int ocb1 = ocb0 + 16;
        h3[m * 128 + ocb1 + 0] = lrelu(acc1.x + c3b[ocb1 + 0]);
        h3[m * 128 + ocb1 + 1] = lrelu(acc1.y + c3b[ocb1 + 1]);
        h3[m * 128 + ocb1 + 2] = lrelu(acc1.z + c3b[ocb1 + 2]);
        h3[m * 128 + ocb1 + 3] = lrelu(acc1.w + c3b[ocb1 + 3]);
    }
    __syncthreads();

    // ---- phase C: conv4 (256 outs) ----
    {
        float a0 = c4b[tid], a1 = a0, a2 = a0, a3 = a0;
        const float* wp = c4w + tid * 128;
        for (int k = 0; k < 128; k += 4) {
            float4 wv = *(const float4*)(wp + k);
            a0 += h3[k] * wv.x + h3[k + 1] * wv.y + h3[k + 2] * wv.z + h3[k + 3] * wv.w;
            a1 += h3[128 + k] * wv.x + h3[128 + k + 1] * wv.y + h3[128 + k + 2] * wv.z + h3[128 + k + 3] * wv.w;
            a2 += h3[256 + k] * wv.x + h3[256 + k + 1] * wv.y + h3[256 + k + 2] * wv.z + h3[256 + k + 3] * wv.w;
            a3 += h3[384 + k] * wv.x + h3[384 + k + 1] * wv.y + h3[384 + k + 2] * wv.z + h3[384 + k + 3] * wv.w;
        }
        h4[tid] = lrelu(a0); h4[256 + tid] = lrelu(a1);
        h4[512 + tid] = lrelu(a2); h4[768 + tid] = lrelu(a3);
    }
    __syncthreads();
    // ---- conv5 (128 outs) ----
    if (tid < 128) {
        float a0 = c5b[tid], a1 = a0, a2 = a0, a3 = a0;
        const float* wp = c5w + tid * 256;
        for (int k = 0; k < 256; k += 4) {
            float4 wv = *(const float4*)(wp + k);
            a0 += h4[k] * wv.x + h4[k + 1] * wv.y + h4[k + 2] * wv.z + h4[k + 3] * wv.w;
            a1 += h4[256 + k] * wv.x + h4[256 + k + 1] * wv.y + h4[256 + k + 2] * wv.z + h4[256 + k + 3] * wv.w;
            a2 += h4[512 + k] * wv.x + h4[512 + k + 1] * wv.y + h4[512 + k + 2] * wv.z + h4[512 + k + 3] * wv.w;
            a3 += h4[768 + k] * wv.x + h4[768 + k + 1] * wv.y + h4[768 + k + 2] * wv.z + h4[768 + k + 3] * wv.w;
        }
        h5[tid] = lrelu(a0); h5[128 + tid] = lrelu(a1);
        h5[256 + tid] = lrelu(a2); h5[384 + tid] = lrelu(a3);
    }
    __syncthreads();
    // ---- dense (512 outs) ----
    for (int o = tid; o < 512; o += 256) {
        float a0 = db[o], a1 = a0, a2 = a0, a3 = a0;
        const float* wp = dw + o * 128;
        for (int k = 0; k < 128; k += 4) {
            float4 wv = *(const float4*)(wp + k);
            a0 += h5[k] * wv.x + h5[k + 1] * wv.y + h5[k + 2] * wv.z + h5[k + 3] * wv.w;
            a1 += h5[128 + k] * wv.x + h5[128 + k + 1] * wv.y + h5[128 + k + 2] * wv.z + h5[128 + k + 3] * wv.w;
            a2 += h5[256 + k] * wv.x + h5[256 + k + 1] * wv.y + h5[256 + k + 2] * wv.z + h5[256 + k + 3] * wv.w;
            a3 += h5[384 + k] * wv.x + h5[384 + k + 1] * wv.y + h5[384 + k + 2] * wv.z + h5[384 + k + 3] * wv.w;
        }
        out[o * 576 + n0 + 0] = a0;
        out[o * 576 + n0 + 1] = a1;
        out[o * 576 + n0 + 2] = a2;
        out[o * 576 + n0 + 3] = a3;
    }
}

extern "C" void kernel_launch(void* const* d_in, const int* in_sizes, int n_in,
                              void* d_out, int out_size, void* d_ws, size_t ws_size,
                              hipStream_t stream) {
    const float* x   = (const float*)d_in[0];
    const float* c1w = (const float*)d_in[1];
    const float* c1b = (const float*)d_in[2];
    const float* c2w = (const float*)d_in[3];
    const float* c2b = (const float*)d_in[4];
    const float* c3w = (const float*)d_in[5];
    const float* c3b = (const float*)d_in[6];
    const float* c4w = (const float*)d_in[7];
    const float* c4b = (const float*)d_in[8];
    const float* c5w = (const float*)d_in[9];
    const float* c5b = (const float*)d_in[10];
    const float* dw  = (const float*)d_in[11];
    const float* db  = (const float*)d_in[12];
    float* out = (float*)d_out;

    float* ws = (float*)d_ws;
    unsigned short* P2 = (unsigned short*)(ws);            // 160000 f32 slots
    unsigned short* Z2 = (unsigned short*)(ws + 160000);   // 112896
    unsigned short* W2 = (unsigned short*)(ws + 272896);   // 204800
    unsigned short* W3 = (unsigned short*)(ws + 477696);   // 204800

    k_front<<<1506, 256, 0, stream>>>(x, c1w, c1b, c2w, c3w, P2, W2, W3);
    k_conv2<<<168, 256, 0, stream>>>(P2, W2, c2b, Z2);
    k_fuse3<<<144, 256, 0, stream>>>(Z2, W3, c3b, c4w, c4b, c5w, c5b, dw, db, out);
}